// Round 1
// baseline (6672.946 us; speedup 1.0000x reference)
//
#include <hip/hip_runtime.h>
#include <hip/hip_bf16.h>
#include <math.h>

#define D_MODEL 512
#define N_HEADS 8
#define D_HEAD  64
#define D_FF    2048
#define SEQ     512
#define BATCH   8
#define ROWS    (BATCH * SEQ)      /* 4096 */
#define PRED_LEN 96
#define KLEN_MASKED (SEQ - PRED_LEN)  /* 416 */
#define LN_EPS  1e-5f

/* ---------------- input projection: out = pos[l] + x @ w + b ---------------- */
__global__ __launch_bounds__(256) void input_proj(
    const float* __restrict__ x, const float* __restrict__ w,
    const float* __restrict__ bias, const float* __restrict__ pos,
    float* __restrict__ out, int in_size)
{
    int idx = blockIdx.x * 256 + threadIdx.x;     /* over ROWS*D_MODEL */
    int col = idx & (D_MODEL - 1);
    int row = idx >> 9;                            /* b*SEQ + l */
    int l   = row & (SEQ - 1);
    const float* xr = x + (size_t)row * in_size;
    float acc = bias[col] + pos[(size_t)l * D_MODEL + col];
    for (int t = 0; t < in_size; ++t) acc += xr[t] * w[(size_t)t * D_MODEL + col];
    out[idx] = acc;
}

/* ---------------- generic tiled GEMM: C = A[M,K] @ W[K,N] (+bias)(+relu) ----- */
/* 64x64 tile, BK=16, 256 threads, 4x4 microtile. M,N,K multiples of 64/16.     */
__global__ __launch_bounds__(256) void gemm_tiled(
    const float* __restrict__ A, const float* __restrict__ W,
    const float* __restrict__ bias, float* __restrict__ C,
    int M, int N, int K, int relu)
{
    __shared__ float As[16][64];   /* [k][m] */
    __shared__ float Bs[16][64];   /* [k][n] */
    int tid  = threadIdx.x;
    int row0 = blockIdx.y * 64;
    int col0 = blockIdx.x * 64;
    int tr = (tid >> 4) << 2;
    int tc = (tid & 15) << 2;
    float acc[4][4] = {};
    for (int k0 = 0; k0 < K; k0 += 16) {
        /* A tile: 64 rows x 16 k; each thread one float4 along k */
        {
            int m = tid >> 2;
            int k = (tid & 3) << 2;
            float4 t = *(const float4*)(A + (size_t)(row0 + m) * K + k0 + k);
            As[k + 0][m] = t.x; As[k + 1][m] = t.y;
            As[k + 2][m] = t.z; As[k + 3][m] = t.w;
        }
        /* B tile: 16 k x 64 n */
        {
            int k = tid >> 4;
            int n = (tid & 15) << 2;
            *(float4*)&Bs[k][n] = *(const float4*)(W + (size_t)(k0 + k) * N + col0 + n);
        }
        __syncthreads();
        #pragma unroll
        for (int k = 0; k < 16; ++k) {
            float a[4], b[4];
            #pragma unroll
            for (int i = 0; i < 4; ++i) a[i] = As[k][tr + i];
            #pragma unroll
            for (int j = 0; j < 4; ++j) b[j] = Bs[k][tc + j];
            #pragma unroll
            for (int i = 0; i < 4; ++i)
                #pragma unroll
                for (int j = 0; j < 4; ++j) acc[i][j] += a[i] * b[j];
        }
        __syncthreads();
    }
    #pragma unroll
    for (int i = 0; i < 4; ++i) {
        #pragma unroll
        for (int j = 0; j < 4; ++j) {
            float v = acc[i][j];
            if (bias) v += bias[col0 + tc + j];
            if (relu) v = fmaxf(v, 0.f);
            C[(size_t)(row0 + tr + i) * N + col0 + tc + j] = v;
        }
    }
}

/* ---------------- attention scores: S[bh,q,k] = Q.K^T / 8 ------------------- */
/* Q,K stored as [ROWS, D_MODEL]; head h at cols h*64..h*64+63.                 */
/* grid: (kt=8, qt=8, bh=64), 256 threads, 64x64 output tile, full D_HEAD LDS.  */
__global__ __launch_bounds__(256) void attn_scores(
    const float* __restrict__ Q, const float* __restrict__ Kb,
    float* __restrict__ S)
{
    __shared__ float Qs[64][65];
    __shared__ float Ks[64][65];
    int bh = blockIdx.z;
    int b  = bh >> 3, h = bh & 7;
    int q0 = blockIdx.y * 64, k0 = blockIdx.x * 64;
    int tid = threadIdx.x;
    const float* Qbase = Q  + ((size_t)(b * SEQ + q0)) * D_MODEL + h * D_HEAD;
    const float* Kbase = Kb + ((size_t)(b * SEQ + k0)) * D_MODEL + h * D_HEAD;
    for (int i = tid; i < 64 * 64; i += 256) {
        int r = i >> 6, d = i & 63;
        Qs[r][d] = Qbase[(size_t)r * D_MODEL + d];
        Ks[r][d] = Kbase[(size_t)r * D_MODEL + d];
    }
    __syncthreads();
    int tq = (tid >> 4) << 2;
    int tk = (tid & 15) << 2;
    float acc[4][4] = {};
    #pragma unroll 8
    for (int d = 0; d < 64; ++d) {
        float a[4], bb[4];
        #pragma unroll
        for (int i = 0; i < 4; ++i) a[i]  = Qs[tq + i][d];
        #pragma unroll
        for (int j = 0; j < 4; ++j) bb[j] = Ks[tk + j][d];
        #pragma unroll
        for (int i = 0; i < 4; ++i)
            #pragma unroll
            for (int j = 0; j < 4; ++j) acc[i][j] += a[i] * bb[j];
    }
    size_t base = ((size_t)bh * SEQ + q0 + tq) * SEQ + k0 + tk;
    #pragma unroll
    for (int i = 0; i < 4; ++i)
        #pragma unroll
        for (int j = 0; j < 4; ++j)
            S[base + (size_t)i * SEQ + j] = acc[i][j] * 0.125f;
}

/* ---------------- row softmax over SEQ cols, valid length klen -------------- */
__global__ __launch_bounds__(256) void softmax_rows(float* __restrict__ S, int klen)
{
    int row = blockIdx.x;
    float* r = S + (size_t)row * SEQ;
    int tid = threadIdx.x;
    float x0 = r[tid];                                        /* klen > 256 always */
    float x1 = (tid + 256 < klen) ? r[tid + 256] : -1e30f;
    __shared__ float red[256];
    red[tid] = fmaxf(x0, x1);
    __syncthreads();
    for (int s = 128; s; s >>= 1) {
        if (tid < s) red[tid] = fmaxf(red[tid], red[tid + s]);
        __syncthreads();
    }
    float m = red[0];
    __syncthreads();
    float e0 = __expf(x0 - m);
    float e1 = (tid + 256 < klen) ? __expf(x1 - m) : 0.f;
    red[tid] = e0 + e1;
    __syncthreads();
    for (int s = 128; s; s >>= 1) {
        if (tid < s) red[tid] += red[tid + s];
        __syncthreads();
    }
    float inv = 1.f / red[0];
    r[tid]       = e0 * inv;
    r[tid + 256] = e1 * inv;
}

/* ---------------- attention context: ctx = P @ V ---------------------------- */
/* grid: (qt=8, bh=64). Block: 64 q x 64 d (full head), 256 threads, BK=32.     */
__global__ __launch_bounds__(256) void attn_ctx(
    const float* __restrict__ S, const float* __restrict__ V,
    float* __restrict__ ctx)
{
    __shared__ float Ps[64][33];
    __shared__ float Vs[32][65];
    int bh = blockIdx.y;
    int b  = bh >> 3, h = bh & 7;
    int q0 = blockIdx.x * 64;
    int tid = threadIdx.x;
    int tq = (tid >> 4) << 2;
    int td = (tid & 15) << 2;
    float acc[4][4] = {};
    for (int k0 = 0; k0 < SEQ; k0 += 32) {
        for (int i = tid; i < 64 * 32; i += 256) {
            int q = i >> 5, kk = i & 31;
            Ps[q][kk] = S[((size_t)bh * SEQ + q0 + q) * SEQ + k0 + kk];
        }
        for (int i = tid; i < 32 * 64; i += 256) {
            int kk = i >> 6, d = i & 63;
            Vs[kk][d] = V[((size_t)(b * SEQ + k0 + kk)) * D_MODEL + h * D_HEAD + d];
        }
        __syncthreads();
        #pragma unroll 8
        for (int kk = 0; kk < 32; ++kk) {
            float a[4], bb[4];
            #pragma unroll
            for (int i = 0; i < 4; ++i) a[i]  = Ps[tq + i][kk];
            #pragma unroll
            for (int j = 0; j < 4; ++j) bb[j] = Vs[kk][td + j];
            #pragma unroll
            for (int i = 0; i < 4; ++i)
                #pragma unroll
                for (int j = 0; j < 4; ++j) acc[i][j] += a[i] * bb[j];
        }
        __syncthreads();
    }
    #pragma unroll
    for (int i = 0; i < 4; ++i)
        #pragma unroll
        for (int j = 0; j < 4; ++j)
            ctx[((size_t)(b * SEQ + q0 + tq + i)) * D_MODEL + h * D_HEAD + td + j] = acc[i][j];
}

/* ---------------- residual add + LayerNorm (in-place capable) --------------- */
__global__ __launch_bounds__(256) void add_ln(
    const float* __restrict__ a, const float* __restrict__ x,
    const float* __restrict__ g, const float* __restrict__ b,
    float* __restrict__ out)
{
    int row = blockIdx.x;
    int tid = threadIdx.x;
    const float* ar = a + (size_t)row * D_MODEL;
    const float* xr = x + (size_t)row * D_MODEL;
    float v0 = ar[tid] + xr[tid];
    float v1 = ar[tid + 256] + xr[tid + 256];
    __shared__ float red[256];
    red[tid] = v0 + v1;
    __syncthreads();
    for (int s = 128; s; s >>= 1) {
        if (tid < s) red[tid] += red[tid + s];
        __syncthreads();
    }
    float mu = red[0] * (1.f / D_MODEL);
    __syncthreads();
    float d0 = v0 - mu, d1 = v1 - mu;
    red[tid] = d0 * d0 + d1 * d1;
    __syncthreads();
    for (int s = 128; s; s >>= 1) {
        if (tid < s) red[tid] += red[tid + s];
        __syncthreads();
    }
    float rs = rsqrtf(red[0] * (1.f / D_MODEL) + LN_EPS);
    out[(size_t)row * D_MODEL + tid]       = d0 * rs * g[tid]       + b[tid];
    out[(size_t)row * D_MODEL + tid + 256] = d1 * rs * g[tid + 256] + b[tid + 256];
}

/* ---------------- final projection: out[ROWS,8] = X @ W + b ----------------- */
__global__ __launch_bounds__(256) void final_proj(
    const float* __restrict__ X, const float* __restrict__ W,
    const float* __restrict__ b, float* __restrict__ out)
{
    int idx = blockIdx.x * 256 + threadIdx.x;   /* 0..ROWS*8-1 */
    int row = idx >> 3, c = idx & 7;
    const float* xr = X + (size_t)row * D_MODEL;
    float acc = b[c];
    for (int t = 0; t < D_MODEL; ++t) acc += xr[t] * W[t * 8 + c];
    out[idx] = acc;
}

/* ============================ host orchestration ============================ */
extern "C" void kernel_launch(void* const* d_in, const int* in_sizes, int n_in,
                              void* d_out, int out_size, void* d_ws, size_t ws_size,
                              hipStream_t stream)
{
    const float* src         = (const float*)d_in[0];
    const float* tgt         = (const float*)d_in[1];
    const float* src_pos     = (const float*)d_in[2];
    const float* tgt_pos     = (const float*)d_in[3];
    const float* src_lin_w   = (const float*)d_in[4];
    const float* src_lin_b   = (const float*)d_in[5];
    const float* tgt_lin_w   = (const float*)d_in[6];
    const float* tgt_lin_b   = (const float*)d_in[7];
    const float* enc_wq      = (const float*)d_in[8];
    const float* enc_wk      = (const float*)d_in[9];
    const float* enc_wv      = (const float*)d_in[10];
    const float* enc_wo      = (const float*)d_in[11];
    const float* enc_ff1_w   = (const float*)d_in[12];
    const float* enc_ff1_b   = (const float*)d_in[13];
    const float* enc_ff2_w   = (const float*)d_in[14];
    const float* enc_ff2_b   = (const float*)d_in[15];
    const float* enc_ln1_g   = (const float*)d_in[16];
    const float* enc_ln1_b   = (const float*)d_in[17];
    const float* enc_ln2_g   = (const float*)d_in[18];
    const float* enc_ln2_b   = (const float*)d_in[19];
    const float* dec_sa_wq   = (const float*)d_in[20];
    const float* dec_sa_wk   = (const float*)d_in[21];
    const float* dec_sa_wv   = (const float*)d_in[22];
    const float* dec_sa_wo   = (const float*)d_in[23];
    const float* dec_ca_wq   = (const float*)d_in[24];
    const float* dec_ca_wk   = (const float*)d_in[25];
    const float* dec_ca_wv   = (const float*)d_in[26];
    const float* dec_ca_wo   = (const float*)d_in[27];
    const float* dec_ff1_w   = (const float*)d_in[28];
    const float* dec_ff1_b   = (const float*)d_in[29];
    const float* dec_ff2_w   = (const float*)d_in[30];
    const float* dec_ff2_b   = (const float*)d_in[31];
    const float* dec_ln1_g   = (const float*)d_in[32];
    const float* dec_ln1_b   = (const float*)d_in[33];
    const float* dec_ln2_g   = (const float*)d_in[34];
    const float* dec_ln2_b   = (const float*)d_in[35];
    const float* dec_ln3_g   = (const float*)d_in[36];
    const float* dec_ln3_b   = (const float*)d_in[37];
    const float* proj_w      = (const float*)d_in[38];
    const float* proj_b      = (const float*)d_in[39];

    float* ws    = (float*)d_ws;
    float* enc_x = ws;                         /* ROWS*D_MODEL */
    float* dec_x = enc_x + (size_t)ROWS * D_MODEL;
    float* q     = dec_x + (size_t)ROWS * D_MODEL;
    float* k     = q     + (size_t)ROWS * D_MODEL;
    float* v     = k     + (size_t)ROWS * D_MODEL;
    float* ctx   = v     + (size_t)ROWS * D_MODEL;
    float* attn  = ctx   + (size_t)ROWS * D_MODEL;
    float* ffh   = attn  + (size_t)ROWS * D_MODEL;          /* ROWS*D_FF */
    float* sc    = ffh   + (size_t)ROWS * D_FF;             /* 64*SEQ*SEQ */

    auto gemm = [&](const float* A, const float* W, const float* bias, float* C,
                    int M, int N, int K, int relu) {
        gemm_tiled<<<dim3(N / 64, M / 64), 256, 0, stream>>>(A, W, bias, C, M, N, K, relu);
    };
    const dim3 sgrid(8, 8, 64);
    const int  nrows_sm = 64 * SEQ;

    /* input projections */
    input_proj<<<ROWS * D_MODEL / 256, 256, 0, stream>>>(src, src_lin_w, src_lin_b,
                                                         src_pos, enc_x, 16);
    input_proj<<<ROWS * D_MODEL / 256, 256, 0, stream>>>(tgt, tgt_lin_w, tgt_lin_b,
                                                         tgt_pos, dec_x, 8);

    /* encoder */
    for (int i = 0; i < 4; ++i) {
        const size_t wo_off = (size_t)i * D_MODEL * D_MODEL;
        gemm(enc_x, enc_wq + wo_off, nullptr, q, ROWS, D_MODEL, D_MODEL, 0);
        gemm(enc_x, enc_wk + wo_off, nullptr, k, ROWS, D_MODEL, D_MODEL, 0);
        gemm(enc_x, enc_wv + wo_off, nullptr, v, ROWS, D_MODEL, D_MODEL, 0);
        attn_scores<<<sgrid, 256, 0, stream>>>(q, k, sc);
        softmax_rows<<<nrows_sm, 256, 0, stream>>>(sc, SEQ);
        attn_ctx<<<dim3(8, 64), 256, 0, stream>>>(sc, v, ctx);
        gemm(ctx, enc_wo + wo_off, nullptr, attn, ROWS, D_MODEL, D_MODEL, 0);
        add_ln<<<ROWS, 256, 0, stream>>>(attn, enc_x, enc_ln1_g + i * D_MODEL,
                                         enc_ln1_b + i * D_MODEL, enc_x);
        gemm(enc_x, enc_ff1_w + (size_t)i * D_MODEL * D_FF, enc_ff1_b + i * D_FF,
             ffh, ROWS, D_FF, D_MODEL, 1);
        gemm(ffh, enc_ff2_w + (size_t)i * D_FF * D_MODEL, enc_ff2_b + i * D_MODEL,
             attn, ROWS, D_MODEL, D_FF, 0);
        add_ln<<<ROWS, 256, 0, stream>>>(attn, enc_x, enc_ln2_g + i * D_MODEL,
                                         enc_ln2_b + i * D_MODEL, enc_x);
    }

    /* decoder */
    for (int i = 0; i < 4; ++i) {
        const size_t wo_off = (size_t)i * D_MODEL * D_MODEL;
        /* masked self-attention */
        gemm(dec_x, dec_sa_wq + wo_off, nullptr, q, ROWS, D_MODEL, D_MODEL, 0);
        gemm(dec_x, dec_sa_wk + wo_off, nullptr, k, ROWS, D_MODEL, D_MODEL, 0);
        gemm(dec_x, dec_sa_wv + wo_off, nullptr, v, ROWS, D_MODEL, D_MODEL, 0);
        attn_scores<<<sgrid, 256, 0, stream>>>(q, k, sc);
        softmax_rows<<<nrows_sm, 256, 0, stream>>>(sc, KLEN_MASKED);
        attn_ctx<<<dim3(8, 64), 256, 0, stream>>>(sc, v, ctx);
        gemm(ctx, dec_sa_wo + wo_off, nullptr, attn, ROWS, D_MODEL, D_MODEL, 0);
        add_ln<<<ROWS, 256, 0, stream>>>(attn, dec_x, dec_ln1_g + i * D_MODEL,
                                         dec_ln1_b + i * D_MODEL, dec_x);
        /* cross-attention (K,V from encoder output) */
        gemm(dec_x, dec_ca_wq + wo_off, nullptr, q, ROWS, D_MODEL, D_MODEL, 0);
        gemm(enc_x, dec_ca_wk + wo_off, nullptr, k, ROWS, D_MODEL, D_MODEL, 0);
        gemm(enc_x, dec_ca_wv + wo_off, nullptr, v, ROWS, D_MODEL, D_MODEL, 0);
        attn_scores<<<sgrid, 256, 0, stream>>>(q, k, sc);
        softmax_rows<<<nrows_sm, 256, 0, stream>>>(sc, SEQ);
        attn_ctx<<<dim3(8, 64), 256, 0, stream>>>(sc, v, ctx);
        gemm(ctx, dec_ca_wo + wo_off, nullptr, attn, ROWS, D_MODEL, D_MODEL, 0);
        add_ln<<<ROWS, 256, 0, stream>>>(attn, dec_x, dec_ln2_g + i * D_MODEL,
                                         dec_ln2_b + i * D_MODEL, dec_x);
        /* feed-forward */
        gemm(dec_x, dec_ff1_w + (size_t)i * D_MODEL * D_FF, dec_ff1_b + i * D_FF,
             ffh, ROWS, D_FF, D_MODEL, 1);
        gemm(ffh, dec_ff2_w + (size_t)i * D_FF * D_MODEL, dec_ff2_b + i * D_MODEL,
             attn, ROWS, D_MODEL, D_FF, 0);
        add_ln<<<ROWS, 256, 0, stream>>>(attn, dec_x, dec_ln3_g + i * D_MODEL,
                                         dec_ln3_b + i * D_MODEL, dec_x);
    }

    /* final projection */
    final_proj<<<ROWS * 8 / 256, 256, 0, stream>>>(dec_x, proj_w, proj_b, (float*)d_out);
}

// Round 2
// 2255.468 us; speedup vs baseline: 2.9586x; 2.9586x over previous
//
#include <hip/hip_runtime.h>
#include <hip/hip_bf16.h>
#include <math.h>

#define D_MODEL 512
#define N_HEADS 8
#define D_HEAD  64
#define D_FF    2048
#define SEQ     512
#define BATCH   8
#define ROWS    (BATCH * SEQ)          /* 4096 */
#define PRED_LEN 96
#define KLEN_MASKED (SEQ - PRED_LEN)   /* 416 */
#define LN_EPS  1e-5f

typedef float  f32x4 __attribute__((ext_vector_type(4)));
typedef short  s16x8 __attribute__((ext_vector_type(8)));

__device__ __forceinline__ float bf2f(ushort u) {
    union { unsigned int i; float f; } c; c.i = ((unsigned int)u) << 16; return c.f;
}
__device__ __forceinline__ ushort f2bf(float v) {
    __hip_bfloat16 h = __float2bfloat16(v);
    return *(ushort*)&h;
}
__device__ __forceinline__ void gl_lds16(const void* g, void* lds) {
    __builtin_amdgcn_global_load_lds(
        (const __attribute__((address_space(1))) unsigned int*)g,
        (__attribute__((address_space(3))) unsigned int*)lds, 16, 0, 0);
}

/* ============ bf16 MFMA GEMM: C = scale*(A @ Bt^T) + bias, opt relu ==========
 * A  [M,K] bf16 row-major (k contiguous), row stride lda
 * Bt [N,K] bf16 row-major (k contiguous), row stride ldb  (i.e. B transposed)
 * C  [M,N] bf16, row stride ldc
 * Batched over gridDim.z: z -> b=z>>3, h=z&7, with per-b / per-h element strides.
 * BM=128, BK=32, 4 waves in 2x2; wave tile 64 x (BN/2). M%128==0, N%BN==0, K%32==0.
 */
template<int BN>
__global__ __launch_bounds__(256) void gemm_mfma(
    const ushort* __restrict__ A, int lda, long sAb, int sAh,
    const ushort* __restrict__ Bt, int ldb, long sBb, int sBh,
    ushort* __restrict__ C, int ldc, long sCb, int sCh,
    int K, const float* __restrict__ bias, int relu, float scale)
{
    constexpr int NW = BN / 32;                 /* 16x16 n-tiles per wave */
    __shared__ __attribute__((aligned(16))) ushort As[128 * 32];
    __shared__ __attribute__((aligned(16))) ushort Bs[BN * 32];
    const int tid = threadIdx.x;
    const int w = tid >> 6, lane = tid & 63;
    const int l16 = lane & 15, quad = lane >> 4;
    const int z = blockIdx.z, b = z >> 3, h = z & 7;
    const int m0 = blockIdx.y * 128, n0 = blockIdx.x * BN;
    const ushort* Ab = A + (long)b * sAb + (long)h * sAh + (long)m0 * lda;
    const ushort* Bb = Bt + (long)b * sBb + (long)h * sBh + (long)n0 * ldb;
    ushort* Cb = C + (long)b * sCb + (long)h * sCh;
    const int wm = (w >> 1) * 64, wn = (w & 1) * (BN / 2);

    f32x4 acc[4][NW];
    #pragma unroll
    for (int i = 0; i < 4; ++i)
        #pragma unroll
        for (int j = 0; j < NW; ++j) acc[i][j] = (f32x4)0.f;

    for (int k0 = 0; k0 < K; k0 += 32) {
        /* A tile 128x32 bf16 = 8KB = 512 x 16B chunks; chunk c -> row c>>2, kchunk c&3 */
        #pragma unroll
        for (int t = 0; t < 2; ++t) {
            int c = (t * 4 + w) * 64 + lane;
            gl_lds16(Ab + (long)(c >> 2) * lda + k0 + (c & 3) * 8,
                     (void*)(As + (size_t)(t * 4 + w) * 64 * 8));
        }
        /* B tile BNx32 */
        #pragma unroll
        for (int t = 0; t < BN / 64; ++t) {
            int c = (t * 4 + w) * 64 + lane;
            gl_lds16(Bb + (long)(c >> 2) * ldb + k0 + (c & 3) * 8,
                     (void*)(Bs + (size_t)(t * 4 + w) * 64 * 8));
        }
        __syncthreads();
        s16x8 af[4];
        #pragma unroll
        for (int i = 0; i < 4; ++i)
            af[i] = *(const s16x8*)(As + (size_t)(wm + i * 16 + l16) * 32 + quad * 8);
        #pragma unroll
        for (int j = 0; j < NW; ++j) {
            s16x8 bfr = *(const s16x8*)(Bs + (size_t)(wn + j * 16 + l16) * 32 + quad * 8);
            #pragma unroll
            for (int i = 0; i < 4; ++i)
                acc[i][j] = __builtin_amdgcn_mfma_f32_16x16x32_bf16(af[i], bfr, acc[i][j], 0, 0, 0);
        }
        __syncthreads();
    }
    /* epilogue: C/D layout col=lane&15, row=quad*4+r */
    #pragma unroll
    for (int i = 0; i < 4; ++i) {
        #pragma unroll
        for (int j = 0; j < NW; ++j) {
            int col = n0 + wn + j * 16 + l16;
            float bv = bias ? bias[col] : 0.f;
            #pragma unroll
            for (int r = 0; r < 4; ++r) {
                float v = acc[i][j][r] * scale + bv;
                if (relu) v = fmaxf(v, 0.f);
                Cb[(long)(m0 + wm + i * 16 + quad * 4 + r) * ldc + col] = f2bf(v);
            }
        }
    }
}

/* ============ weight repack: fp32 [K][N] -> bf16 [N][K] ============ */
__global__ __launch_bounds__(256) void wtrans(const float* __restrict__ in,
                                              ushort* __restrict__ out, int K, int N)
{
    __shared__ float t[32][33];
    int n0 = blockIdx.x * 32, k0 = blockIdx.y * 32;
    int tx = threadIdx.x & 31, ty = threadIdx.x >> 5;
    #pragma unroll
    for (int r = 0; r < 4; ++r)
        t[ty + r * 8][tx] = in[(long)(k0 + ty + r * 8) * N + n0 + tx];
    __syncthreads();
    #pragma unroll
    for (int r = 0; r < 4; ++r)
        out[(long)(n0 + ty + r * 8) * K + k0 + tx] = f2bf(t[tx][ty + r * 8]);
}

/* ============ V transpose per head: v[b*SEQ+p][h*64+d] -> vt[bh][d][p] ======= */
__global__ __launch_bounds__(256) void vtrans(const ushort* __restrict__ v, int ldv,
                                              ushort* __restrict__ vt)
{
    __shared__ ushort t[32][33];
    int p0 = blockIdx.x * 32, d0 = blockIdx.y * 32;
    int bh = blockIdx.z, b = bh >> 3, h = bh & 7;
    int tx = threadIdx.x & 31, ty = threadIdx.x >> 5;
    #pragma unroll
    for (int r = 0; r < 4; ++r)
        t[ty + r * 8][tx] = v[(long)(b * SEQ + p0 + ty + r * 8) * ldv + h * D_HEAD + d0 + tx];
    __syncthreads();
    #pragma unroll
    for (int r = 0; r < 4; ++r)
        vt[((long)bh * D_HEAD + d0 + ty + r * 8) * SEQ + p0 + tx] = t[tx][ty + r * 8];
}

/* ============ input projection: out = pos[l] + x @ w + b (fp32 + bf16) ====== */
__global__ __launch_bounds__(256) void input_proj(
    const float* __restrict__ x, const float* __restrict__ w,
    const float* __restrict__ bias, const float* __restrict__ pos,
    float* __restrict__ out32, ushort* __restrict__ outb, int in_size)
{
    int idx = blockIdx.x * 256 + threadIdx.x;
    int col = idx & (D_MODEL - 1);
    int row = idx >> 9;
    int l   = row & (SEQ - 1);
    const float* xr = x + (size_t)row * in_size;
    float acc = bias[col] + pos[(size_t)l * D_MODEL + col];
    for (int t = 0; t < in_size; ++t) acc += xr[t] * w[(size_t)t * D_MODEL + col];
    out32[idx] = acc;
    outb[idx]  = f2bf(acc);
}

/* ============ softmax over rows of [.., SEQ] bf16, valid length klen ======== */
__global__ __launch_bounds__(256) void softmax_rows(ushort* __restrict__ S, int klen)
{
    int row = blockIdx.x;
    ushort* r = S + (size_t)row * SEQ;
    int tid = threadIdx.x;
    float x0 = bf2f(r[tid]);
    float x1 = (tid + 256 < klen) ? bf2f(r[tid + 256]) : -1e30f;
    __shared__ float red[256];
    red[tid] = fmaxf(x0, x1);
    __syncthreads();
    for (int s = 128; s; s >>= 1) {
        if (tid < s) red[tid] = fmaxf(red[tid], red[tid + s]);
        __syncthreads();
    }
    float m = red[0];
    __syncthreads();
    float e0 = __expf(x0 - m);
    float e1 = (tid + 256 < klen) ? __expf(x1 - m) : 0.f;
    red[tid] = e0 + e1;
    __syncthreads();
    for (int s = 128; s; s >>= 1) {
        if (tid < s) red[tid] += red[tid + s];
        __syncthreads();
    }
    float inv = 1.f / red[0];
    r[tid]       = f2bf(e0 * inv);
    r[tid + 256] = f2bf(e1 * inv);
}

/* ============ residual add + LayerNorm: fp32 residual carrier =============== */
__global__ __launch_bounds__(256) void add_ln(
    const ushort* __restrict__ a, const float* __restrict__ x,
    const float* __restrict__ g, const float* __restrict__ b,
    float* __restrict__ out32, ushort* __restrict__ outb)
{
    int row = blockIdx.x;
    int tid = threadIdx.x;
    const ushort* ar = a + (size_t)row * D_MODEL;
    const float*  xr = x + (size_t)row * D_MODEL;
    float v0 = bf2f(ar[tid]) + xr[tid];
    float v1 = bf2f(ar[tid + 256]) + xr[tid + 256];
    __shared__ float red[256];
    red[tid] = v0 + v1;
    __syncthreads();
    for (int s = 128; s; s >>= 1) {
        if (tid < s) red[tid] += red[tid + s];
        __syncthreads();
    }
    float mu = red[0] * (1.f / D_MODEL);
    __syncthreads();
    float d0 = v0 - mu, d1 = v1 - mu;
    red[tid] = d0 * d0 + d1 * d1;
    __syncthreads();
    for (int s = 128; s; s >>= 1) {
        if (tid < s) red[tid] += red[tid + s];
        __syncthreads();
    }
    float rs = rsqrtf(red[0] * (1.f / D_MODEL) + LN_EPS);
    float y0 = d0 * rs * g[tid]       + b[tid];
    float y1 = d1 * rs * g[tid + 256] + b[tid + 256];
    size_t base = (size_t)row * D_MODEL;
    out32[base + tid] = y0;        out32[base + tid + 256] = y1;
    outb[base + tid]  = f2bf(y0);  outb[base + tid + 256]  = f2bf(y1);
}

/* ============ final projection: out[ROWS,8] = X32 @ W + b (fp32) =========== */
__global__ __launch_bounds__(256) void final_proj(
    const float* __restrict__ X, const float* __restrict__ W,
    const float* __restrict__ b, float* __restrict__ out)
{
    int idx = blockIdx.x * 256 + threadIdx.x;
    int row = idx >> 3, c = idx & 7;
    const float* xr = X + (size_t)row * D_MODEL;
    float acc = b[c];
    for (int t = 0; t < D_MODEL; ++t) acc += xr[t] * W[t * 8 + c];
    out[idx] = acc;
}

/* ============================ host orchestration ============================ */
extern "C" void kernel_launch(void* const* d_in, const int* in_sizes, int n_in,
                              void* d_out, int out_size, void* d_ws, size_t ws_size,
                              hipStream_t stream)
{
    const float* src         = (const float*)d_in[0];
    const float* tgt         = (const float*)d_in[1];
    const float* src_pos     = (const float*)d_in[2];
    const float* tgt_pos     = (const float*)d_in[3];
    const float* src_lin_w   = (const float*)d_in[4];
    const float* src_lin_b   = (const float*)d_in[5];
    const float* tgt_lin_w   = (const float*)d_in[6];
    const float* tgt_lin_b   = (const float*)d_in[7];
    const float* enc_wq      = (const float*)d_in[8];
    const float* enc_wk      = (const float*)d_in[9];
    const float* enc_wv      = (const float*)d_in[10];
    const float* enc_wo      = (const float*)d_in[11];
    const float* enc_ff1_w   = (const float*)d_in[12];
    const float* enc_ff1_b   = (const float*)d_in[13];
    const float* enc_ff2_w   = (const float*)d_in[14];
    const float* enc_ff2_b   = (const float*)d_in[15];
    const float* enc_ln1_g   = (const float*)d_in[16];
    const float* enc_ln1_b   = (const float*)d_in[17];
    const float* enc_ln2_g   = (const float*)d_in[18];
    const float* enc_ln2_b   = (const float*)d_in[19];
    const float* dec_sa_wq   = (const float*)d_in[20];
    const float* dec_sa_wk   = (const float*)d_in[21];
    const float* dec_sa_wv   = (const float*)d_in[22];
    const float* dec_sa_wo   = (const float*)d_in[23];
    const float* dec_ca_wq   = (const float*)d_in[24];
    const float* dec_ca_wk   = (const float*)d_in[25];
    const float* dec_ca_wv   = (const float*)d_in[26];
    const float* dec_ca_wo   = (const float*)d_in[27];
    const float* dec_ff1_w   = (const float*)d_in[28];
    const float* dec_ff1_b   = (const float*)d_in[29];
    const float* dec_ff2_w   = (const float*)d_in[30];
    const float* dec_ff2_b   = (const float*)d_in[31];
    const float* dec_ln1_g   = (const float*)d_in[32];
    const float* dec_ln1_b   = (const float*)d_in[33];
    const float* dec_ln2_g   = (const float*)d_in[34];
    const float* dec_ln2_b   = (const float*)d_in[35];
    const float* dec_ln3_g   = (const float*)d_in[36];
    const float* dec_ln3_b   = (const float*)d_in[37];
    const float* proj_w      = (const float*)d_in[38];
    const float* proj_b      = (const float*)d_in[39];

    /* ---- workspace carve ---- */
    char* p = (char*)d_ws;
    auto carve = [&](size_t bytes) { char* r = p; p += (bytes + 255) & ~(size_t)255; return r; };
    ushort* enc_xb = (ushort*)carve((size_t)ROWS * D_MODEL * 2);
    ushort* dec_xb = (ushort*)carve((size_t)ROWS * D_MODEL * 2);
    float*  enc_x32= (float*) carve((size_t)ROWS * D_MODEL * 4);
    float*  dec_x32= (float*) carve((size_t)ROWS * D_MODEL * 4);
    ushort* qkvb   = (ushort*)carve((size_t)ROWS * 1536 * 2);
    ushort* qb     = (ushort*)carve((size_t)ROWS * D_MODEL * 2);
    ushort* kvb    = (ushort*)carve((size_t)ROWS * 1024 * 2);
    ushort* ctxb   = (ushort*)carve((size_t)ROWS * D_MODEL * 2);
    ushort* attnb  = (ushort*)carve((size_t)ROWS * D_MODEL * 2);
    ushort* probs  = (ushort*)carve((size_t)64 * SEQ * SEQ * 2);
    ushort* ffhb   = (ushort*)carve((size_t)ROWS * D_FF * 2);
    ushort* vt     = (ushort*)carve((size_t)64 * D_HEAD * SEQ * 2);
    ushort* wt_qkv = (ushort*)carve((size_t)1536 * 512 * 2);
    ushort* wt_o   = (ushort*)carve((size_t)512 * 512 * 2);
    ushort* wt_ff1 = (ushort*)carve((size_t)2048 * 512 * 2);
    ushort* wt_ff2 = (ushort*)carve((size_t)512 * 2048 * 2);
    ushort* wt_q   = (ushort*)carve((size_t)512 * 512 * 2);
    ushort* wt_kv  = (ushort*)carve((size_t)1024 * 512 * 2);

    const long SQQ = (long)SEQ * SEQ;              /* 262144 */
    const dim3 blk(256);

    auto g128 = [&](const ushort* A, int lda, long sAb, int sAh,
                    const ushort* Bt, int ldb, long sBb, int sBh,
                    ushort* C, int ldc, long sCb, int sCh,
                    int M, int N, int K, const float* bias, int relu, float scale, int Z) {
        gemm_mfma<128><<<dim3(N / 128, M / 128, Z), blk, 0, stream>>>(
            A, lda, sAb, sAh, Bt, ldb, sBb, sBh, C, ldc, sCb, sCh, K, bias, relu, scale);
    };
    auto g64 = [&](const ushort* A, int lda, long sAb, int sAh,
                   const ushort* Bt, int ldb, long sBb, int sBh,
                   ushort* C, int ldc, long sCb, int sCh,
                   int M, int N, int K, const float* bias, int relu, float scale, int Z) {
        gemm_mfma<64><<<dim3(N / 64, M / 128, Z), blk, 0, stream>>>(
            A, lda, sAb, sAh, Bt, ldb, sBb, sBh, C, ldc, sCb, sCh, K, bias, relu, scale);
    };
    auto wt = [&](const float* in, ushort* out, int K, int N) {
        wtrans<<<dim3(N / 32, K / 32), blk, 0, stream>>>(in, out, K, N);
    };

    /* input projections */
    input_proj<<<ROWS * D_MODEL / 256, blk, 0, stream>>>(src, src_lin_w, src_lin_b,
                                                         src_pos, enc_x32, enc_xb, 16);
    input_proj<<<ROWS * D_MODEL / 256, blk, 0, stream>>>(tgt, tgt_lin_w, tgt_lin_b,
                                                         tgt_pos, dec_x32, dec_xb, 8);

    /* attention helper: x_q/x_kv bf16 [ROWS,512]; writes attnb */
    auto attention = [&](const ushort* q_src_qkv, int qlda, long qsAb,
                         const ushort* k_src, int klda, long ksAb,
                         const ushort* v_src, int vlda,
                         int klen) {
        /* scores -> probs */
        g128(q_src_qkv, qlda, qsAb, D_HEAD,
             k_src, klda, ksAb, D_HEAD,
             probs, SEQ, 8 * SQQ, SQQ,
             SEQ, SEQ, D_HEAD, nullptr, 0, 0.125f, 64);
        softmax_rows<<<64 * SEQ, blk, 0, stream>>>(probs, klen);
        vtrans<<<dim3(SEQ / 32, D_HEAD / 32, 64), blk, 0, stream>>>(v_src, vlda, vt);
        g64(probs, SEQ, 8 * SQQ, SQQ,
            vt, SEQ, (long)8 * D_HEAD * SEQ, D_HEAD * SEQ,
            ctxb, D_MODEL, (long)SEQ * D_MODEL, D_HEAD,
            SEQ, D_HEAD, SEQ, nullptr, 0, 1.f, 64);
    };

    /* ===================== encoder ===================== */
    for (int i = 0; i < 4; ++i) {
        const long wo512 = (long)i * 512 * 512;
        wt(enc_wq + wo512, wt_qkv,            512, 512);
        wt(enc_wk + wo512, wt_qkv + 262144,   512, 512);
        wt(enc_wv + wo512, wt_qkv + 524288,   512, 512);
        g128(enc_xb, 512, 0, 0, wt_qkv, 512, 0, 0, qkvb, 1536, 0, 0,
             ROWS, 1536, 512, nullptr, 0, 1.f, 1);
        attention(qkvb, 1536, (long)SEQ * 1536,
                  qkvb + 512, 1536, (long)SEQ * 1536,
                  qkvb + 1024, 1536, SEQ);
        wt(enc_wo + wo512, wt_o, 512, 512);
        g64(ctxb, 512, 0, 0, wt_o, 512, 0, 0, attnb, 512, 0, 0,
            ROWS, 512, 512, nullptr, 0, 1.f, 1);
        add_ln<<<ROWS, blk, 0, stream>>>(attnb, enc_x32, enc_ln1_g + i * 512,
                                         enc_ln1_b + i * 512, enc_x32, enc_xb);
        wt(enc_ff1_w + (long)i * 512 * 2048, wt_ff1, 512, 2048);
        g128(enc_xb, 512, 0, 0, wt_ff1, 512, 0, 0, ffhb, 2048, 0, 0,
             ROWS, 2048, 512, enc_ff1_b + i * 2048, 1, 1.f, 1);
        wt(enc_ff2_w + (long)i * 2048 * 512, wt_ff2, 2048, 512);
        g64(ffhb, 2048, 0, 0, wt_ff2, 2048, 0, 0, attnb, 512, 0, 0,
            ROWS, 512, 2048, enc_ff2_b + i * 512, 0, 1.f, 1);
        add_ln<<<ROWS, blk, 0, stream>>>(attnb, enc_x32, enc_ln2_g + i * 512,
                                         enc_ln2_b + i * 512, enc_x32, enc_xb);
    }

    /* ===================== decoder ===================== */
    for (int i = 0; i < 4; ++i) {
        const long wo512 = (long)i * 512 * 512;
        /* masked self-attention */
        wt(dec_sa_wq + wo512, wt_qkv,          512, 512);
        wt(dec_sa_wk + wo512, wt_qkv + 262144, 512, 512);
        wt(dec_sa_wv + wo512, wt_qkv + 524288, 512, 512);
        g128(dec_xb, 512, 0, 0, wt_qkv, 512, 0, 0, qkvb, 1536, 0, 0,
             ROWS, 1536, 512, nullptr, 0, 1.f, 1);
        attention(qkvb, 1536, (long)SEQ * 1536,
                  qkvb + 512, 1536, (long)SEQ * 1536,
                  qkvb + 1024, 1536, KLEN_MASKED);
        wt(dec_sa_wo + wo512, wt_o, 512, 512);
        g64(ctxb, 512, 0, 0, wt_o, 512, 0, 0, attnb, 512, 0, 0,
            ROWS, 512, 512, nullptr, 0, 1.f, 1);
        add_ln<<<ROWS, blk, 0, stream>>>(attnb, dec_x32, dec_ln1_g + i * 512,
                                         dec_ln1_b + i * 512, dec_x32, dec_xb);
        /* cross-attention */
        wt(dec_ca_wq + wo512, wt_q, 512, 512);
        g64(dec_xb, 512, 0, 0, wt_q, 512, 0, 0, qb, 512, 0, 0,
            ROWS, 512, 512, nullptr, 0, 1.f, 1);
        wt(dec_ca_wk + wo512, wt_kv,          512, 512);
        wt(dec_ca_wv + wo512, wt_kv + 262144, 512, 512);
        g128(enc_xb, 512, 0, 0, wt_kv, 512, 0, 0, kvb, 1024, 0, 0,
             ROWS, 1024, 512, nullptr, 0, 1.f, 1);
        attention(qb, 512, (long)SEQ * 512,
                  kvb, 1024, (long)SEQ * 1024,
                  kvb + 512, 1024, SEQ);
        wt(dec_ca_wo + wo512, wt_o, 512, 512);
        g64(ctxb, 512, 0, 0, wt_o, 512, 0, 0, attnb, 512, 0, 0,
            ROWS, 512, 512, nullptr, 0, 1.f, 1);
        add_ln<<<ROWS, blk, 0, stream>>>(attnb, dec_x32, dec_ln2_g + i * 512,
                                         dec_ln2_b + i * 512, dec_x32, dec_xb);
        /* feed-forward */
        wt(dec_ff1_w + (long)i * 512 * 2048, wt_ff1, 512, 2048);
        g128(dec_xb, 512, 0, 0, wt_ff1, 512, 0, 0, ffhb, 2048, 0, 0,
             ROWS, 2048, 512, dec_ff1_b + i * 2048, 1, 1.f, 1);
        wt(dec_ff2_w + (long)i * 2048 * 512, wt_ff2, 2048, 512);
        g64(ffhb, 2048, 0, 0, wt_ff2, 2048, 0, 0, attnb, 512, 0, 0,
            ROWS, 512, 2048, dec_ff2_b + i * 512, 0, 1.f, 1);
        add_ln<<<ROWS, blk, 0, stream>>>(attnb, dec_x32, dec_ln3_g + i * 512,
                                         dec_ln3_b + i * 512, dec_x32, dec_xb);
    }

    /* final projection (fp32 path) */
    final_proj<<<ROWS * 8 / 256, blk, 0, stream>>>(dec_x32, proj_w, proj_b, (float*)d_out);
}

// Round 3
// 1609.888 us; speedup vs baseline: 4.1450x; 1.4010x over previous
//
#include <hip/hip_runtime.h>
#include <hip/hip_bf16.h>
#include <math.h>

#define D_MODEL 512
#define N_HEADS 8
#define D_HEAD  64
#define D_FF    2048
#define SEQ     512
#define BATCH   8
#define ROWS    (BATCH * SEQ)          /* 4096 */
#define PRED_LEN 96
#define KLEN_MASKED (SEQ - PRED_LEN)   /* 416 */
#define LN_EPS  1e-5f

typedef float  f32x4 __attribute__((ext_vector_type(4)));
typedef short  s16x8 __attribute__((ext_vector_type(8)));

__device__ __forceinline__ float bf2f(ushort u) {
    union { unsigned int i; float f; } c; c.i = ((unsigned int)u) << 16; return c.f;
}
__device__ __forceinline__ ushort f2bf(float v) {
    __hip_bfloat16 h = __float2bfloat16(v);
    return *(ushort*)&h;
}
__device__ __forceinline__ void gl_lds16(const void* g, void* lds) {
    __builtin_amdgcn_global_load_lds(
        (const __attribute__((address_space(1))) unsigned int*)g,
        (__attribute__((address_space(3))) unsigned int*)lds, 16, 0, 0);
}

/* ============ bf16 MFMA GEMM: C = scale*(A @ Bt^T) + bias, opt relu ==========
 * A  [M,K] bf16 row-major, row stride lda;  Bt [N,K] bf16 row-major (k-contig)
 * C  [M,N] bf16, row stride ldc.  BM=128, BK=32, 4 waves 2x2.
 */
template<int BN>
__global__ __launch_bounds__(256) void gemm_mfma(
    const ushort* __restrict__ A, int lda,
    const ushort* __restrict__ Bt, int ldb,
    ushort* __restrict__ C, int ldc,
    int K, const float* __restrict__ bias, int relu, float scale)
{
    constexpr int NW = BN / 32;
    __shared__ __attribute__((aligned(16))) ushort As[128 * 32];
    __shared__ __attribute__((aligned(16))) ushort Bs[BN * 32];
    const int tid = threadIdx.x;
    const int w = tid >> 6, lane = tid & 63;
    const int l16 = lane & 15, quad = lane >> 4;
    const int m0 = blockIdx.y * 128, n0 = blockIdx.x * BN;
    const ushort* Ab = A + (size_t)m0 * lda;
    const ushort* Bb = Bt + (size_t)n0 * ldb;
    const int wm = (w >> 1) * 64, wn = (w & 1) * (BN / 2);

    f32x4 acc[4][NW];
    #pragma unroll
    for (int i = 0; i < 4; ++i)
        #pragma unroll
        for (int j = 0; j < NW; ++j) acc[i][j] = (f32x4)0.f;

    for (int k0 = 0; k0 < K; k0 += 32) {
        #pragma unroll
        for (int t = 0; t < 2; ++t) {
            int c = (t * 4 + w) * 64 + lane;
            gl_lds16(Ab + (size_t)(c >> 2) * lda + k0 + (c & 3) * 8,
                     (void*)(As + (size_t)(t * 4 + w) * 512));
        }
        #pragma unroll
        for (int t = 0; t < BN / 64; ++t) {
            int c = (t * 4 + w) * 64 + lane;
            gl_lds16(Bb + (size_t)(c >> 2) * ldb + k0 + (c & 3) * 8,
                     (void*)(Bs + (size_t)(t * 4 + w) * 512));
        }
        __syncthreads();
        s16x8 af[4];
        #pragma unroll
        for (int i = 0; i < 4; ++i)
            af[i] = *(const s16x8*)(As + (size_t)(wm + i * 16 + l16) * 32 + quad * 8);
        #pragma unroll
        for (int j = 0; j < NW; ++j) {
            s16x8 bfr = *(const s16x8*)(Bs + (size_t)(wn + j * 16 + l16) * 32 + quad * 8);
            #pragma unroll
            for (int i = 0; i < 4; ++i)
                acc[i][j] = __builtin_amdgcn_mfma_f32_16x16x32_bf16(af[i], bfr, acc[i][j], 0, 0, 0);
        }
        __syncthreads();
    }
    #pragma unroll
    for (int i = 0; i < 4; ++i) {
        #pragma unroll
        for (int j = 0; j < NW; ++j) {
            int col = n0 + wn + j * 16 + l16;
            float bv = bias ? bias[col] : 0.f;
            #pragma unroll
            for (int r = 0; r < 4; ++r) {
                float v = acc[i][j][r] * scale + bv;
                if (relu) v = fmaxf(v, 0.f);
                C[(size_t)(m0 + wm + i * 16 + quad * 4 + r) * ldc + col] = f2bf(v);
            }
        }
    }
}

/* ============ flash attention: O = softmax(Q K^T / 8, klen) V ================
 * Q [b*SEQ+q][ldq] (head at +h*64), K likewise, Vt [bh][64][SEQ] (pre-transposed)
 * grid (SEQ/64, 64), 256 thr. Per wave: 16 q rows, full 512-wide scores in regs.
 */
__global__ __launch_bounds__(256) void flash_attn(
    const ushort* __restrict__ Q, int ldq,
    const ushort* __restrict__ K, int ldk,
    const ushort* __restrict__ Vt,
    ushort* __restrict__ O, int ldo, int klen)
{
    __shared__ __attribute__((aligned(16))) ushort KVs[8192];   /* 16 KB staging */
    __shared__ __attribute__((aligned(16))) ushort Es[4][2048]; /* per-wave E chunk */
    const int tid = threadIdx.x, w = tid >> 6, lane = tid & 63;
    const int l16 = lane & 15, quad = lane >> 4;
    const int bh = blockIdx.y, b = bh >> 3, h = bh & 7;
    const int q0 = blockIdx.x * 64;

    const ushort* Qb = Q + (size_t)(b * SEQ) * ldq + h * D_HEAD;
    const ushort* Kb = K + (size_t)(b * SEQ) * ldk + h * D_HEAD;

    s16x8 af0, af1;
    {
        const ushort* qr = Qb + (size_t)(q0 + w * 16 + l16) * ldq + quad * 8;
        af0 = *(const s16x8*)(qr);
        af1 = *(const s16x8*)(qr + 32);
    }

    f32x4 sc[32];

    /* ---- scores: S = Q K^T (raw; scale folded into softmax) ---- */
    #pragma unroll
    for (int kc = 0; kc < 4; ++kc) {
        #pragma unroll
        for (int it = 0; it < 4; ++it) {
            int cc = (it * 4 + w) * 64 + lane;
            int row = cc >> 3;
            int dch = (cc & 7) ^ (row & 7);          /* XOR swizzle */
            gl_lds16(Kb + (size_t)(kc * 128 + row) * ldk + dch * 8,
                     (void*)(KVs + (size_t)(it * 4 + w) * 512));
        }
        __syncthreads();
        #pragma unroll
        for (int kt = 0; kt < 8; ++kt) {
            int r0 = kt * 16 + l16;
            s16x8 b0 = *(const s16x8*)(KVs + r0 * 64 + ((quad)     ^ (r0 & 7)) * 8);
            s16x8 b1 = *(const s16x8*)(KVs + r0 * 64 + ((4 + quad) ^ (r0 & 7)) * 8);
            f32x4 a = __builtin_amdgcn_mfma_f32_16x16x32_bf16(af0, b0, (f32x4)0.f, 0, 0, 0);
            sc[kc * 8 + kt] = __builtin_amdgcn_mfma_f32_16x16x32_bf16(af1, b1, a, 0, 0, 0);
        }
        __syncthreads();
    }

    /* ---- softmax (per q-row; row lives in the 16 lanes of one quad) ---- */
    float inv[4];
    #pragma unroll
    for (int r = 0; r < 4; ++r) {
        float m = -1e30f;
        #pragma unroll
        for (int j = 0; j < 32; ++j) {
            bool valid = (j * 16 + l16) < klen;
            m = valid ? fmaxf(m, sc[j][r]) : m;
        }
        m = fmaxf(m, __shfl_xor(m, 1));
        m = fmaxf(m, __shfl_xor(m, 2));
        m = fmaxf(m, __shfl_xor(m, 4));
        m = fmaxf(m, __shfl_xor(m, 8));
        float ssum = 0.f;
        #pragma unroll
        for (int j = 0; j < 32; ++j) {
            bool valid = (j * 16 + l16) < klen;
            float e = valid ? __expf((sc[j][r] - m) * 0.125f) : 0.f;
            sc[j][r] = e;
            ssum += e;
        }
        ssum += __shfl_xor(ssum, 1);
        ssum += __shfl_xor(ssum, 2);
        ssum += __shfl_xor(ssum, 4);
        ssum += __shfl_xor(ssum, 8);
        inv[r] = 1.f / ssum;
    }

    /* ---- PV: O = (E V) * inv ---- */
    f32x4 oacc[4];
    #pragma unroll
    for (int jd = 0; jd < 4; ++jd) oacc[jd] = (f32x4)0.f;
    const ushort* Vb = Vt + (size_t)bh * (D_HEAD * SEQ);
    #pragma unroll
    for (int kc = 0; kc < 4; ++kc) {
        #pragma unroll
        for (int it = 0; it < 4; ++it) {
            int cc = (it * 4 + w) * 64 + lane;
            int d = cc >> 4;
            int kch = (cc & 15) ^ (d & 15);
            gl_lds16(Vb + (size_t)d * SEQ + kc * 128 + kch * 8,
                     (void*)(KVs + (size_t)(it * 4 + w) * 512));
        }
        /* E chunk -> per-wave LDS in A-layout (XOR-swizzled 16B chunks) */
        #pragma unroll
        for (int j = 0; j < 8; ++j) {
            int lcj = j * 2 + (l16 >> 3);
            #pragma unroll
            for (int r = 0; r < 4; ++r) {
                int m = quad * 4 + r;
                Es[w][m * 128 + (lcj ^ m) * 8 + (l16 & 7)] = f2bf(sc[kc * 8 + j][r]);
            }
        }
        __syncthreads();
        #pragma unroll
        for (int ks = 0; ks < 4; ++ks) {
            int lc = ks * 4 + quad;
            s16x8 ea = *(const s16x8*)(&Es[w][l16 * 128 + (lc ^ l16) * 8]);
            #pragma unroll
            for (int jd = 0; jd < 4; ++jd) {
                int row = jd * 16 + l16;
                s16x8 vb = *(const s16x8*)(KVs + row * 128 + (lc ^ l16) * 8);
                oacc[jd] = __builtin_amdgcn_mfma_f32_16x16x32_bf16(ea, vb, oacc[jd], 0, 0, 0);
            }
        }
        __syncthreads();
    }

    ushort* Ob = O + (size_t)(b * SEQ) * ldo + h * D_HEAD;
    #pragma unroll
    for (int jd = 0; jd < 4; ++jd)
        #pragma unroll
        for (int r = 0; r < 4; ++r)
            Ob[(size_t)(q0 + w * 16 + quad * 4 + r) * ldo + jd * 16 + l16] =
                f2bf(oacc[jd][r] * inv[r]);
}

/* ============ batched weight repacks ============ */
struct AttnPtrs { const float* p[48]; };
struct FfPtrs   { const float* p[16]; };

__global__ __launch_bounds__(256) void repack_attn(AttnPtrs L, ushort* __restrict__ out)
{
    int z = blockIdx.z;
    const float* in = L.p[z];
    ushort* o = out + (size_t)z * 262144;
    __shared__ float t[32][33];
    int n0 = blockIdx.x * 32, k0 = blockIdx.y * 32;
    int tx = threadIdx.x & 31, ty = threadIdx.x >> 5;
    #pragma unroll
    for (int r = 0; r < 4; ++r)
        t[ty + r * 8][tx] = in[(size_t)(k0 + ty + r * 8) * 512 + n0 + tx];
    __syncthreads();
    #pragma unroll
    for (int r = 0; r < 4; ++r)
        o[(size_t)(n0 + ty + r * 8) * 512 + k0 + tx] = f2bf(t[tx][ty + r * 8]);
}

__global__ __launch_bounds__(256) void repack_ff(FfPtrs L, ushort* __restrict__ out)
{
    int z = blockIdx.y;
    int Kd = (z < 8) ? 512 : 2048, Nd = (z < 8) ? 2048 : 512;
    const float* in = L.p[z];
    ushort* o = out + (size_t)z * (512 * 2048);
    int t = blockIdx.x;
    int tn = Nd / 32;
    int n0 = (t % tn) * 32, k0 = (t / tn) * 32;
    __shared__ float ts[32][33];
    int tx = threadIdx.x & 31, ty = threadIdx.x >> 5;
    #pragma unroll
    for (int r = 0; r < 4; ++r)
        ts[ty + r * 8][tx] = in[(size_t)(k0 + ty + r * 8) * Nd + n0 + tx];
    __syncthreads();
    #pragma unroll
    for (int r = 0; r < 4; ++r)
        o[(size_t)(n0 + ty + r * 8) * Kd + k0 + tx] = f2bf(ts[tx][ty + r * 8]);
}

/* ============ V transpose per head: v[b*SEQ+p][h*64+d] -> vt[bh][d][p] ====== */
__global__ __launch_bounds__(256) void vtrans(const ushort* __restrict__ v, int ldv,
                                              ushort* __restrict__ vt)
{
    __shared__ ushort t[32][33];
    int p0 = blockIdx.x * 32, d0 = blockIdx.y * 32;
    int bh = blockIdx.z, b = bh >> 3, h = bh & 7;
    int tx = threadIdx.x & 31, ty = threadIdx.x >> 5;
    #pragma unroll
    for (int r = 0; r < 4; ++r)
        t[ty + r * 8][tx] = v[(size_t)(b * SEQ + p0 + ty + r * 8) * ldv + h * D_HEAD + d0 + tx];
    __syncthreads();
    #pragma unroll
    for (int r = 0; r < 4; ++r)
        vt[((size_t)bh * D_HEAD + d0 + ty + r * 8) * SEQ + p0 + tx] = t[tx][ty + r * 8];
}

/* ============ input projection ============ */
__global__ __launch_bounds__(256) void input_proj(
    const float* __restrict__ x, const float* __restrict__ w,
    const float* __restrict__ bias, const float* __restrict__ pos,
    float* __restrict__ out32, ushort* __restrict__ outb, int in_size)
{
    int idx = blockIdx.x * 256 + threadIdx.x;
    int col = idx & (D_MODEL - 1);
    int row = idx >> 9;
    int l   = row & (SEQ - 1);
    const float* xr = x + (size_t)row * in_size;
    float acc = bias[col] + pos[(size_t)l * D_MODEL + col];
    for (int t = 0; t < in_size; ++t) acc += xr[t] * w[(size_t)t * D_MODEL + col];
    out32[idx] = acc;
    outb[idx]  = f2bf(acc);
}

/* ============ residual add + LayerNorm (fp32 carrier) ============ */
__global__ __launch_bounds__(256) void add_ln(
    const ushort* __restrict__ a, const float* __restrict__ x,
    const float* __restrict__ g, const float* __restrict__ b,
    float* __restrict__ out32, ushort* __restrict__ outb)
{
    int row = blockIdx.x;
    int tid = threadIdx.x;
    const ushort* ar = a + (size_t)row * D_MODEL;
    const float*  xr = x + (size_t)row * D_MODEL;
    float v0 = bf2f(ar[tid]) + xr[tid];
    float v1 = bf2f(ar[tid + 256]) + xr[tid + 256];
    __shared__ float red[256];
    red[tid] = v0 + v1;
    __syncthreads();
    for (int s = 128; s; s >>= 1) {
        if (tid < s) red[tid] += red[tid + s];
        __syncthreads();
    }
    float mu = red[0] * (1.f / D_MODEL);
    __syncthreads();
    float d0 = v0 - mu, d1 = v1 - mu;
    red[tid] = d0 * d0 + d1 * d1;
    __syncthreads();
    for (int s = 128; s; s >>= 1) {
        if (tid < s) red[tid] += red[tid + s];
        __syncthreads();
    }
    float rs = rsqrtf(red[0] * (1.f / D_MODEL) + LN_EPS);
    float y0 = d0 * rs * g[tid]       + b[tid];
    float y1 = d1 * rs * g[tid + 256] + b[tid + 256];
    size_t base = (size_t)row * D_MODEL;
    out32[base + tid] = y0;        out32[base + tid + 256] = y1;
    outb[base + tid]  = f2bf(y0);  outb[base + tid + 256]  = f2bf(y1);
}

/* ============ final projection ============ */
__global__ __launch_bounds__(256) void final_proj(
    const float* __restrict__ X, const float* __restrict__ W,
    const float* __restrict__ b, float* __restrict__ out)
{
    int idx = blockIdx.x * 256 + threadIdx.x;
    int row = idx >> 3, c = idx & 7;
    const float* xr = X + (size_t)row * D_MODEL;
    float acc = b[c];
    for (int t = 0; t < D_MODEL; ++t) acc += xr[t] * W[t * 8 + c];
    out[idx] = acc;
}

/* ============================ host orchestration ============================ */
extern "C" void kernel_launch(void* const* d_in, const int* in_sizes, int n_in,
                              void* d_out, int out_size, void* d_ws, size_t ws_size,
                              hipStream_t stream)
{
    const float* src         = (const float*)d_in[0];
    const float* tgt         = (const float*)d_in[1];
    const float* src_pos     = (const float*)d_in[2];
    const float* tgt_pos     = (const float*)d_in[3];
    const float* src_lin_w   = (const float*)d_in[4];
    const float* src_lin_b   = (const float*)d_in[5];
    const float* tgt_lin_w   = (const float*)d_in[6];
    const float* tgt_lin_b   = (const float*)d_in[7];
    const float* enc_wq      = (const float*)d_in[8];
    const float* enc_wk      = (const float*)d_in[9];
    const float* enc_wv      = (const float*)d_in[10];
    const float* enc_wo      = (const float*)d_in[11];
    const float* enc_ff1_w   = (const float*)d_in[12];
    const float* enc_ff1_b   = (const float*)d_in[13];
    const float* enc_ff2_w   = (const float*)d_in[14];
    const float* enc_ff2_b   = (const float*)d_in[15];
    const float* enc_ln1_g   = (const float*)d_in[16];
    const float* enc_ln1_b   = (const float*)d_in[17];
    const float* enc_ln2_g   = (const float*)d_in[18];
    const float* enc_ln2_b   = (const float*)d_in[19];
    const float* dec_sa_wq   = (const float*)d_in[20];
    const float* dec_sa_wk   = (const float*)d_in[21];
    const float* dec_sa_wv   = (const float*)d_in[22];
    const float* dec_sa_wo   = (const float*)d_in[23];
    const float* dec_ca_wq   = (const float*)d_in[24];
    const float* dec_ca_wk   = (const float*)d_in[25];
    const float* dec_ca_wv   = (const float*)d_in[26];
    const float* dec_ca_wo   = (const float*)d_in[27];
    const float* dec_ff1_w   = (const float*)d_in[28];
    const float* dec_ff1_b   = (const float*)d_in[29];
    const float* dec_ff2_w   = (const float*)d_in[30];
    const float* dec_ff2_b   = (const float*)d_in[31];
    const float* dec_ln1_g   = (const float*)d_in[32];
    const float* dec_ln1_b   = (const float*)d_in[33];
    const float* dec_ln2_g   = (const float*)d_in[34];
    const float* dec_ln2_b   = (const float*)d_in[35];
    const float* dec_ln3_g   = (const float*)d_in[36];
    const float* dec_ln3_b   = (const float*)d_in[37];
    const float* proj_w      = (const float*)d_in[38];
    const float* proj_b      = (const float*)d_in[39];

    /* ---- workspace carve ---- */
    char* p = (char*)d_ws;
    auto carve = [&](size_t bytes) { char* r = p; p += (bytes + 255) & ~(size_t)255; return r; };
    ushort* enc_xb = (ushort*)carve((size_t)ROWS * D_MODEL * 2);
    ushort* dec_xb = (ushort*)carve((size_t)ROWS * D_MODEL * 2);
    float*  enc_x32= (float*) carve((size_t)ROWS * D_MODEL * 4);
    float*  dec_x32= (float*) carve((size_t)ROWS * D_MODEL * 4);
    ushort* qkvb   = (ushort*)carve((size_t)ROWS * 1536 * 2);
    ushort* qb     = (ushort*)carve((size_t)ROWS * D_MODEL * 2);
    ushort* kvb    = (ushort*)carve((size_t)ROWS * 1024 * 2);
    ushort* ctxb   = (ushort*)carve((size_t)ROWS * D_MODEL * 2);
    ushort* attnb  = (ushort*)carve((size_t)ROWS * D_MODEL * 2);
    ushort* ffhb   = (ushort*)carve((size_t)ROWS * D_FF * 2);
    ushort* vt     = (ushort*)carve((size_t)64 * D_HEAD * SEQ * 2);
    ushort* wa     = (ushort*)carve((size_t)48 * 262144 * 2);
    ushort* wf     = (ushort*)carve((size_t)16 * 1048576 * 2);

    const dim3 blk(256);

    /* ---- weight repack (2 launches) ---- */
    {
        AttnPtrs A;
        for (int i = 0; i < 4; ++i) {
            const size_t o = (size_t)i * 262144;
            A.p[i * 3 + 0] = enc_wq + o;  A.p[i * 3 + 1] = enc_wk + o;  A.p[i * 3 + 2] = enc_wv + o;
            A.p[12 + i] = enc_wo + o;
            A.p[16 + i * 3 + 0] = dec_sa_wq + o; A.p[16 + i * 3 + 1] = dec_sa_wk + o;
            A.p[16 + i * 3 + 2] = dec_sa_wv + o;
            A.p[28 + i] = dec_sa_wo + o;
            A.p[32 + i * 2 + 0] = dec_ca_wk + o; A.p[32 + i * 2 + 1] = dec_ca_wv + o;
            A.p[40 + i] = dec_ca_wq + o;
            A.p[44 + i] = dec_ca_wo + o;
        }
        repack_attn<<<dim3(16, 16, 48), blk, 0, stream>>>(A, wa);
        FfPtrs F;
        for (int i = 0; i < 4; ++i) {
            F.p[0 + i]  = enc_ff1_w + (size_t)i * 1048576;
            F.p[4 + i]  = dec_ff1_w + (size_t)i * 1048576;
            F.p[8 + i]  = enc_ff2_w + (size_t)i * 1048576;
            F.p[12 + i] = dec_ff2_w + (size_t)i * 1048576;
        }
        repack_ff<<<dim3(1024, 16), blk, 0, stream>>>(F, wf);
    }

    auto g128 = [&](const ushort* A, int lda, const ushort* Bt, int ldb,
                    ushort* C, int ldc, int M, int N, int K,
                    const float* bias, int relu) {
        gemm_mfma<128><<<dim3(N / 128, M / 128), blk, 0, stream>>>(
            A, lda, Bt, ldb, C, ldc, K, bias, relu, 1.f);
    };
    auto g64 = [&](const ushort* A, int lda, const ushort* Bt, int ldb,
                   ushort* C, int ldc, int M, int N, int K,
                   const float* bias, int relu) {
        gemm_mfma<64><<<dim3(N / 64, M / 128), blk, 0, stream>>>(
            A, lda, Bt, ldb, C, ldc, K, bias, relu, 1.f);
    };
    auto attention = [&](const ushort* q_src, int ldq_, const ushort* k_src, int ldk_,
                         const ushort* v_src, int ldv_, int klen) {
        vtrans<<<dim3(16, 2, 64), blk, 0, stream>>>(v_src, ldv_, vt);
        flash_attn<<<dim3(8, 64), blk, 0, stream>>>(q_src, ldq_, k_src, ldk_, vt,
                                                    ctxb, D_MODEL, klen);
    };

    /* input projections */
    input_proj<<<ROWS * D_MODEL / 256, blk, 0, stream>>>(src, src_lin_w, src_lin_b,
                                                         src_pos, enc_x32, enc_xb, 16);
    input_proj<<<ROWS * D_MODEL / 256, blk, 0, stream>>>(tgt, tgt_lin_w, tgt_lin_b,
                                                         tgt_pos, dec_x32, dec_xb, 8);

    /* ===================== encoder ===================== */
    for (int i = 0; i < 4; ++i) {
        g128(enc_xb, 512, wa + (size_t)(i * 3) * 262144, 512, qkvb, 1536,
             ROWS, 1536, 512, nullptr, 0);
        attention(qkvb, 1536, qkvb + 512, 1536, qkvb + 1024, 1536, SEQ);
        g64(ctxb, 512, wa + (size_t)(12 + i) * 262144, 512, attnb, 512,
            ROWS, 512, 512, nullptr, 0);
        add_ln<<<ROWS, blk, 0, stream>>>(attnb, enc_x32, enc_ln1_g + i * 512,
                                         enc_ln1_b + i * 512, enc_x32, enc_xb);
        g128(enc_xb, 512, wf + (size_t)i * 1048576, 512, ffhb, 2048,
             ROWS, 2048, 512, enc_ff1_b + i * 2048, 1);
        g64(ffhb, 2048, wf + (size_t)(8 + i) * 1048576, 2048, attnb, 512,
            ROWS, 512, 2048, enc_ff2_b + i * 512, 0);
        add_ln<<<ROWS, blk, 0, stream>>>(attnb, enc_x32, enc_ln2_g + i * 512,
                                         enc_ln2_b + i * 512, enc_x32, enc_xb);
    }

    /* ===================== decoder ===================== */
    for (int i = 0; i < 4; ++i) {
        /* masked self-attention */
        g128(dec_xb, 512, wa + (size_t)(16 + i * 3) * 262144, 512, qkvb, 1536,
             ROWS, 1536, 512, nullptr, 0);
        attention(qkvb, 1536, qkvb + 512, 1536, qkvb + 1024, 1536, KLEN_MASKED);
        g64(ctxb, 512, wa + (size_t)(28 + i) * 262144, 512, attnb, 512,
            ROWS, 512, 512, nullptr, 0);
        add_ln<<<ROWS, blk, 0, stream>>>(attnb, dec_x32, dec_ln1_g + i * 512,
                                         dec_ln1_b + i * 512, dec_x32, dec_xb);
        /* cross-attention */
        g64(dec_xb, 512, wa + (size_t)(40 + i) * 262144, 512, qb, 512,
            ROWS, 512, 512, nullptr, 0);
        g128(enc_xb, 512, wa + (size_t)(32 + i * 2) * 262144, 512, kvb, 1024,
             ROWS, 1024, 512, nullptr, 0);
        attention(qb, 512, kvb, 1024, kvb + 512, 1024, SEQ);
        g64(ctxb, 512, wa + (size_t)(44 + i) * 262144, 512, attnb, 512,
            ROWS, 512, 512, nullptr, 0);
        add_ln<<<ROWS, blk, 0, stream>>>(attnb, dec_x32, dec_ln2_g + i * 512,
                                         dec_ln2_b + i * 512, dec_x32, dec_xb);
        /* feed-forward */
        g128(dec_xb, 512, wf + (size_t)(4 + i) * 1048576, 512, ffhb, 2048,
             ROWS, 2048, 512, dec_ff1_b + i * 2048, 1);
        g64(ffhb, 2048, wf + (size_t)(12 + i) * 1048576, 2048, attnb, 512,
            ROWS, 512, 2048, dec_ff2_b + i * 512, 0);
        add_ln<<<ROWS, blk, 0, stream>>>(attnb, dec_x32, dec_ln3_g + i * 512,
                                         dec_ln3_b + i * 512, dec_x32, dec_xb);
    }

    /* final projection */
    final_proj<<<ROWS * 8 / 256, blk, 0, stream>>>(dec_x32, proj_w, proj_b, (float*)d_out);
}